// Round 6
// baseline (32.677 us; speedup 1.0000x reference)
//
#include <hip/hip_runtime.h>
#include <math.h>

#define NB 16          // batch
#define NT 512         // time
#define NC 32          // channels
#define NW 128         // window
#define TILE_T 32
#define NTILES (NT / TILE_T)        // 16
#define NBLK (NB * NTILES)          // 256
#define NROWS (TILE_T + NW)         // 160 rows staged per block
#define XS 36                       // tile row stride (dwords): 16B-aligned, odd granule step
#define WIN_MIN_F 2.0f
#define WIN_RANGE_F 62.0f

// ws layout (floats):
#define WS_FMEAN 0
#define WS_FSTD  (NB*NT*NC)
#define WS_PART  (2*NB*NT*NC)       // NBLK * 4 * NC

__device__ __forceinline__ float fast_sigmoid_neg(float a) {
    // sigmoid(-a) = 1/(1+exp(a))
    return __builtin_amdgcn_rcpf(1.0f + __expf(a));
}
__device__ __forceinline__ float4 f4mul(const float4 a, const float4 b) {
    float4 r; r.x=a.x*b.x; r.y=a.y*b.y; r.z=a.z*b.z; r.w=a.w*b.w; return r;
}
__device__ __forceinline__ float4 f4fma(const float4 a, const float4 b, const float4 c) {
    float4 r; r.x=fmaf(a.x,b.x,c.x); r.y=fmaf(a.y,b.y,c.y);
    r.z=fmaf(a.z,b.z,c.z); r.w=fmaf(a.w,b.w,c.w); return r;
}

// thread map: tid = (rg<<6) | (wc<<3) | c4g
//   rg  = tid>>6      : row group (4 rows each)  -> wave id
//   wc  = (tid>>3)&7  : w-chunk (16 w's each), lane bits 3..5 -> shfl_xor reduce
//   c4g = tid&7       : channel quad
__global__ __launch_bounds__(512, 2) void feat_main(
    const float* __restrict__ series,
    const int*   __restrict__ indices,
    const float* __restrict__ rwm,
    const float* __restrict__ rws,
    float* __restrict__ f_mean,
    float* __restrict__ f_std,
    float* __restrict__ partials)
{
    __shared__ __align__(16) float s_x [NROWS * XS];   // 23 KB, [row][c] stride 36
    __shared__ __align__(16) float s_w1[NW * NC];      // 16 KB, [w][c]
    __shared__ __align__(16) float s_w2[NW * NC];      // 16 KB, [w][c]
    __shared__ float s_win[2 * NC];
    __shared__ float s_tmp[256];
    __shared__ float s_inv[2 * NC];
    __shared__ float s_q[8 * 4 * NC];                  // [rg][stat][c], 4 KB

    const int tid = threadIdx.x;
    const int blk = blockIdx.x;
    const int b   = blk >> 4;
    const int tt  = blk & 15;
    const int t0  = tt * TILE_T;
    const int start = indices[2 * b];

    // per-channel soft window sizes
    if (tid < 2 * NC) {
        const float raw = (tid < NC) ? rwm[tid] : rws[tid - NC];
        s_win[tid] = WIN_MIN_F + WIN_RANGE_F * fast_sigmoid_neg(-raw);
    }

    // ---- stage series slice rows [start-NW+t0, +NROWS), row-major stride XS ----
    const float4* g4 = (const float4*)(series + (size_t)(start - NW + t0) * NC);
#pragma unroll
    for (int k = 0; k < 3; ++k) {
        const int j = tid + k * 512;            // 1280 float4s total
        if (j < NROWS * 8) {
            const float4 v = g4[j];
            const int row = j >> 3, cq = (j & 7) << 2;
            *(float4*)&s_x[row * XS + cq] = v;
        }
    }
    __syncthreads();   // S1: s_win + tile visible

    // ---- weight tables [w][c]: w(age) = 1/(1+exp(age-win)) ----
#pragma unroll
    for (int k = 0; k < 8; ++k) {
        const int i = tid + k * 512;            // < 4096, i = w*32+c
        const int w = i >> 5, c = i & 31;
        const float age = (float)(NW - 1 - w);
        s_w1[i] = fast_sigmoid_neg(age - s_win[c]);
        s_w2[i] = fast_sigmoid_neg(age - s_win[NC + c]);
    }
    __syncthreads();   // S2: tables visible

    // ---- weight-sum partials (4 quarters per table per channel) ----
    if (tid < 256) {
        const int c = tid & 31, q = tid >> 5;   // q 0..7
        const float* wt = (q < 4) ? s_w1 : s_w2;
        const int w0 = (q & 3) * 32;
        float s = 0.f;
        for (int w = w0; w < w0 + 32; ++w) s += wt[w * NC + c];
        s_tmp[tid] = s;
    }
    __syncthreads();   // S3
    if (tid < 64) {
        const int c = tid & 31, tb = tid >> 5;
        const float s = s_tmp[tb * 128 + c] + s_tmp[tb * 128 + 32 + c]
                      + s_tmp[tb * 128 + 64 + c] + s_tmp[tb * 128 + 96 + c];
        s_inv[tid] = __builtin_amdgcn_rcpf(s);
    }
    __syncthreads();   // S4: s_inv visible to all

    // ---- main loop: 16 w-steps, all-b128, sliding x/x^2 register file ----
    const int rg  = tid >> 6;
    const int wc  = (tid >> 3) & 7;
    const int c4  = (tid & 7) << 2;
    const int R   = rg * 4;
    const int wg0 = wc * 16;

    float4 acc1[4], acc2[4], acc3[4];
#pragma unroll
    for (int k = 0; k < 4; ++k) {
        acc1[k] = make_float4(0.f,0.f,0.f,0.f);
        acc2[k] = make_float4(0.f,0.f,0.f,0.f);
        acc3[k] = make_float4(0.f,0.f,0.f,0.f);
    }

    const float* xp = s_x + (R + wg0) * XS + c4;
    float4 xs[4], qs[4];
#pragma unroll
    for (int i = 0; i < 4; ++i) {
        xs[i] = *(const float4*)(xp + i * XS);
        qs[i] = f4mul(xs[i], xs[i]);
    }

#pragma unroll
    for (int s = 0; s < 16; ++s) {
        const float4 wv1 = *(const float4*)&s_w1[(wg0 + s) * NC + c4];
        const float4 wv2 = *(const float4*)&s_w2[(wg0 + s) * NC + c4];
#pragma unroll
        for (int k = 0; k < 4; ++k) {
            const float4 xv = xs[(s + k) & 3];
            const float4 qv = qs[(s + k) & 3];
            acc1[k] = f4fma(xv, wv1, acc1[k]);
            acc2[k] = f4fma(xv, wv2, acc2[k]);
            acc3[k] = f4fma(qv, wv2, acc3[k]);
        }
        const float4 xn = *(const float4*)(xp + (s + 4) * XS);
        xs[s & 3] = xn;
        qs[s & 3] = f4mul(xn, xn);
    }

    // ---- reduce across w-chunks: shfl_xor over lane bits 3..5 ----
#pragma unroll
    for (int m = 8; m < 64; m <<= 1) {
#pragma unroll
        for (int k = 0; k < 4; ++k) {
            acc1[k].x += __shfl_xor(acc1[k].x, m); acc1[k].y += __shfl_xor(acc1[k].y, m);
            acc1[k].z += __shfl_xor(acc1[k].z, m); acc1[k].w += __shfl_xor(acc1[k].w, m);
            acc2[k].x += __shfl_xor(acc2[k].x, m); acc2[k].y += __shfl_xor(acc2[k].y, m);
            acc2[k].z += __shfl_xor(acc2[k].z, m); acc2[k].w += __shfl_xor(acc2[k].w, m);
            acc3[k].x += __shfl_xor(acc3[k].x, m); acc3[k].y += __shfl_xor(acc3[k].y, m);
            acc3[k].z += __shfl_xor(acc3[k].z, m); acc3[k].w += __shfl_xor(acc3[k].w, m);
        }
    }

    // ---- owners (wc==0): fm/fs + BN per-block stats ----
    if (wc == 0) {
        const float4 i1 = *(const float4*)&s_inv[c4];
        const float4 i2 = *(const float4*)&s_inv[NC + c4];
        float4 st0 = make_float4(0.f,0.f,0.f,0.f), st1 = st0, st2 = st0, st3 = st0;
#pragma unroll
        for (int k = 0; k < 4; ++k) {
            const float4 fm = f4mul(acc1[k], i1);
            const float4 m2 = f4mul(acc2[k], i2);
            float4 var;
            var.x = fmaxf(acc3[k].x * i2.x - m2.x * m2.x, 0.f);
            var.y = fmaxf(acc3[k].y * i2.y - m2.y * m2.y, 0.f);
            var.z = fmaxf(acc3[k].z * i2.z - m2.z * m2.z, 0.f);
            var.w = fmaxf(acc3[k].w * i2.w - m2.w * m2.w, 0.f);
            float4 fs;
            fs.x = sqrtf(var.x + 1e-8f); fs.y = sqrtf(var.y + 1e-8f);
            fs.z = sqrtf(var.z + 1e-8f); fs.w = sqrtf(var.w + 1e-8f);
            const size_t o = ((size_t)(b * NT + t0 + R + k)) * NC + c4;
            *(float4*)&f_mean[o] = fm;
            *(float4*)&f_std[o]  = fs;
            st0.x += fm.x; st0.y += fm.y; st0.z += fm.z; st0.w += fm.w;
            st1 = f4fma(fm, fm, st1);
            st2.x += fs.x; st2.y += fs.y; st2.z += fs.z; st2.w += fs.w;
            st3 = f4fma(fs, fs, st3);
        }
        *(float4*)&s_q[(rg * 4 + 0) * NC + c4] = st0;
        *(float4*)&s_q[(rg * 4 + 1) * NC + c4] = st1;
        *(float4*)&s_q[(rg * 4 + 2) * NC + c4] = st2;
        *(float4*)&s_q[(rg * 4 + 3) * NC + c4] = st3;
    }
    __syncthreads();   // S5

    if (tid < 128) {
        const int stat = tid >> 5, c = tid & 31;
        float s = 0.f;
#pragma unroll
        for (int g = 0; g < 8; ++g) s += s_q[(g * 4 + stat) * NC + c];
        partials[blk * (4 * NC) + stat * NC + c] = s;
    }
}

// BN-reduce (redundant per block) + writeout. 256 blocks x 192 threads, 32 rows each.
__global__ __launch_bounds__(192) void bn_write(
    const float* __restrict__ x,
    const float* __restrict__ f_mean,
    const float* __restrict__ f_std,
    const float* __restrict__ partials,
    const float* __restrict__ gm, const float* __restrict__ bm,
    const float* __restrict__ gs, const float* __restrict__ bs,
    float* __restrict__ out)
{
    __shared__ __align__(16) float s_part[6 * 128];
    __shared__ __align__(16) float s_sums[128];
    __shared__ __align__(16) float s_coef[4 * NC];

    const int tid = threadIdx.x;

    {
        const int cell  = tid & 31;
        const int slice = tid >> 5;
        const int bb0 = slice * 43;
        const int bb1 = (bb0 + 43 > NBLK) ? NBLK : bb0 + 43;
        const float4* p4 = (const float4*)partials;
        float4 acc = {0.f, 0.f, 0.f, 0.f};
        for (int bb = bb0; bb < bb1; ++bb) {
            const float4 v = p4[bb * 32 + cell];
            acc.x += v.x; acc.y += v.y; acc.z += v.z; acc.w += v.w;
        }
        *(float4*)&s_part[(slice * 32 + cell) * 4] = acc;
    }
    __syncthreads();
    if (tid < 32) {
        float4 s = {0.f, 0.f, 0.f, 0.f};
#pragma unroll
        for (int sl = 0; sl < 6; ++sl) {
            const float4 v = ((const float4*)s_part)[sl * 32 + tid];
            s.x += v.x; s.y += v.y; s.z += v.z; s.w += v.w;
        }
        ((float4*)s_sums)[tid] = s;
    }
    __syncthreads();
    if (tid < NC) {
        const float invN = 1.0f / (float)(NB * NT);
        const float mu_m  = s_sums[tid] * invN;
        float var_m = s_sums[32 + tid] * invN - mu_m * mu_m;
        var_m = fmaxf(var_m, 0.0f);
        const float A1 = gm[tid] / sqrtf(var_m + 1e-5f);
        const float B1 = bm[tid] - mu_m * A1;
        const float mu_s  = s_sums[64 + tid] * invN;
        float var_s = s_sums[96 + tid] * invN - mu_s * mu_s;
        var_s = fmaxf(var_s, 0.0f);
        const float A2 = gs[tid] / sqrtf(var_s + 1e-5f);
        const float B2 = bs[tid] - mu_s * A2;
        s_coef[tid]          = A1;
        s_coef[NC + tid]     = B1;
        s_coef[2 * NC + tid] = A2;
        s_coef[3 * NC + tid] = B2;
    }
    __syncthreads();

    const float4* x4  = (const float4*)x;
    const float4* fm4 = (const float4*)f_mean;
    const float4* fs4 = (const float4*)f_std;
    const float4* cf4 = (const float4*)s_coef;
    float4* out4 = (float4*)out;
    const int row0 = blockIdx.x * 32;

#pragma unroll
    for (int k = 0; k < 4; ++k) {
        const int idx = tid + k * 192;           // < 768 = 32 rows * 24
        const int r = idx / 24;
        const int q = idx - r * 24;
        const int row = row0 + r;
        float4 v;
        if (q < 8) {
            v = x4[row * 8 + q];
        } else if (q < 16) {
            const int m = q - 8;
            const float4 f = fm4[row * 8 + m];
            const float4 A = cf4[m], Bv = cf4[8 + m];
            v.x = fmaf(f.x, A.x, Bv.x); v.y = fmaf(f.y, A.y, Bv.y);
            v.z = fmaf(f.z, A.z, Bv.z); v.w = fmaf(f.w, A.w, Bv.w);
        } else {
            const int m = q - 16;
            const float4 f = fs4[row * 8 + m];
            const float4 A = cf4[16 + m], Bv = cf4[24 + m];
            v.x = fmaf(f.x, A.x, Bv.x); v.y = fmaf(f.y, A.y, Bv.y);
            v.z = fmaf(f.z, A.z, Bv.z); v.w = fmaf(f.w, A.w, Bv.w);
        }
        out4[row * 24 + q] = v;
    }
}

extern "C" void kernel_launch(void* const* d_in, const int* in_sizes, int n_in,
                              void* d_out, int out_size, void* d_ws, size_t ws_size,
                              hipStream_t stream) {
    const float* x      = (const float*)d_in[0];
    const float* series = (const float*)d_in[1];
    const int*   idx    = (const int*)d_in[2];
    const float* rwm    = (const float*)d_in[3];
    const float* rws    = (const float*)d_in[4];
    const float* gm     = (const float*)d_in[5];
    const float* bm     = (const float*)d_in[6];
    const float* gs     = (const float*)d_in[7];
    const float* bs     = (const float*)d_in[8];
    float* out = (float*)d_out;
    float* ws  = (float*)d_ws;

    float* f_mean   = ws + WS_FMEAN;
    float* f_std    = ws + WS_FSTD;
    float* partials = ws + WS_PART;

    feat_main<<<NBLK, 512, 0, stream>>>(series, idx, rwm, rws, f_mean, f_std, partials);
    bn_write<<<NBLK, 192, 0, stream>>>(x, f_mean, f_std, partials, gm, bm, gs, bs, out);
}

// Round 7
// 18.333 us; speedup vs baseline: 1.7824x; 1.7824x over previous
//
#include <hip/hip_runtime.h>
#include <math.h>

#define NB 16          // batch
#define NT 512         // time
#define NC 32          // channels
#define NW 128         // window
#define TILE_T 32
#define NTILES (NT / TILE_T)        // 16
#define NBLK (NB * NTILES)          // 256 blocks -> one per CU
#define NROWS (TILE_T + NW)         // 160 rows staged per block
#define WIN_MIN_F 2.0f
#define WIN_RANGE_F 62.0f
#define EINV_F 0.36787944117f       // e^-1

// ws layout (floats):
#define WS_FMEAN 0
#define WS_FSTD  (NB*NT*NC)
#define WS_PART  (2*NB*NT*NC)       // NBLK * 4 * NC

__device__ __forceinline__ float fast_sigmoid_neg(float a) {
    // sigmoid(-a) = 1/(1+exp(a))
    return __builtin_amdgcn_rcpf(1.0f + __expf(a));
}

__global__ __launch_bounds__(256) void feat_main(
    const float* __restrict__ series,
    const int*   __restrict__ indices,
    const float* __restrict__ rwm,
    const float* __restrict__ rws,
    float* __restrict__ f_mean,
    float* __restrict__ f_std,
    float* __restrict__ partials)
{
    // row-major stride 32: lanes = consecutive c -> 2 lanes/bank (free, m136);
    // tg groups differ by rows (stride 128 dwords ≡ 0 mod 32) -> still 2 lanes/bank total. Proven in R4.
    __shared__ __align__(16) float s_x [NROWS * NC];     // 20 KB
    __shared__ float s_w1[NW * NC];                      // 16 KB [w][c]
    __shared__ float s_w2[NW * NC];                      // 16 KB [w][c]
    __shared__ float s_win[2 * NC];
    __shared__ float s_red[4 * 8 * NC];                  // 4 KB

    const int tid = threadIdx.x;
    const int blk = blockIdx.x;
    const int b   = blk >> 4;          // / NTILES
    const int tt  = blk & 15;
    const int t0  = tt * TILE_T;
    const int start = indices[2 * b];

    // per-channel soft window sizes (one fast sigmoid each)
    if (tid < 2 * NC) {
        const float raw = (tid < NC) ? rwm[tid] : rws[tid - NC];
        s_win[tid] = WIN_MIN_F + WIN_RANGE_F * fast_sigmoid_neg(-raw);
    }

    // ---- stage contiguous series slice: rows [start-NW+t0, +NROWS) ----
    const float4* src4 = (const float4*)(series + (size_t)(start - NW + t0) * NC);
    float4* dst4 = (float4*)s_x;
#pragma unroll
    for (int k = 0; k < 5; ++k) {
        const int j = tid + k * 256;       // exactly 1280 float4s
        dst4[j] = src4[j];
    }
    __syncthreads();   // S1: s_win + tile visible

    // ---- weight tables via exp-recurrence: thread owns (c, 16-w chunk) ----
    // w[w][c] = sigmoid(win - age) = 1/(1+exp(age-win)), age = 127-w.
    // E_{w+1} = E_w * e^-1. E=inf (overflow) -> rcp(1+inf)=0 == true weight.
    {
        const int c  = tid & 31;
        const int wc = tid >> 5;           // 0..7
        const int w0 = wc * 16;
        const float age0 = (float)(NW - 1 - w0);
        float E1 = __expf(age0 - s_win[c]);
        float E2 = __expf(age0 - s_win[NC + c]);
#pragma unroll
        for (int j = 0; j < 16; ++j) {
            const int idx = (w0 + j) * NC + c;
            s_w1[idx] = __builtin_amdgcn_rcpf(1.0f + E1);
            s_w2[idx] = __builtin_amdgcn_rcpf(1.0f + E2);
            E1 *= EINV_F;
            E2 *= EINV_F;
        }
    }
    __syncthreads();   // S2: tables visible

    // ---- main compute (R4-proven): thread owns channel c, 4 t-rows; sliding regs ----
    const int c  = tid & 31;
    const int tg = tid >> 5;           // 0..7
    const int tbase = tg * 4;

    float a1[4], a2[4], a3[4], xs[4], xq[4];
#pragma unroll
    for (int k = 0; k < 4; ++k) {
        a1[k] = 0.f; a2[k] = 0.f; a3[k] = 0.f;
        xs[k] = s_x[(tbase + k) * NC + c];
        xq[k] = xs[k] * xs[k];
    }

    float s1 = 0.f, s2 = 0.f;
#pragma unroll 8
    for (int w = 0; w < NW; ++w) {
        const float w1 = s_w1[w * NC + c];
        const float w2 = s_w2[w * NC + c];
        s1 += w1; s2 += w2;
#pragma unroll
        for (int k = 0; k < 4; ++k) {
            a1[k] = fmaf(xs[k], w1, a1[k]);
            a2[k] = fmaf(xs[k], w2, a2[k]);
            a3[k] = fmaf(xq[k], w2, a3[k]);
        }
        xs[0] = xs[1]; xs[1] = xs[2]; xs[2] = xs[3];
        xq[0] = xq[1]; xq[1] = xq[2]; xq[2] = xq[3];
        const float xn = s_x[(tbase + 4 + w) * NC + c];   // max row 159: in bounds
        xs[3] = xn; xq[3] = xn * xn;
    }

    const float inv1 = __builtin_amdgcn_rcpf(s1);
    const float inv2 = __builtin_amdgcn_rcpf(s2);

    float p0 = 0.f, p1 = 0.f, p2 = 0.f, p3 = 0.f;
#pragma unroll
    for (int k = 0; k < 4; ++k) {
        const float fm = a1[k] * inv1;
        const float m2 = a2[k] * inv2;
        float var = a3[k] * inv2 - m2 * m2;
        var = fmaxf(var, 0.0f);
        const float fs = sqrtf(var + 1e-8f);
        const int t = t0 + tbase + k;
        const size_t o = ((size_t)b * NT + t) * NC + c;
        f_mean[o] = fm;
        f_std[o]  = fs;
        p0 += fm; p1 += fm * fm; p2 += fs; p3 += fs * fs;
    }

    s_red[(0 * 8 + tg) * NC + c] = p0;
    s_red[(1 * 8 + tg) * NC + c] = p1;
    s_red[(2 * 8 + tg) * NC + c] = p2;
    s_red[(3 * 8 + tg) * NC + c] = p3;
    __syncthreads();   // S3

    if (tid < 4 * NC) {
        const int a = tid >> 5, cc = tid & 31;
        float s = 0.f;
#pragma unroll
        for (int g = 0; g < 8; ++g) s += s_red[(a * 8 + g) * NC + cc];
        partials[blk * (4 * NC) + a * NC + cc] = s;
    }
}

// BN-reduce (redundant per block) + float4 writeout. 256 blocks x 256 threads, 32 rows each.
__global__ __launch_bounds__(256) void bn_write(
    const float* __restrict__ x,
    const float* __restrict__ f_mean,
    const float* __restrict__ f_std,
    const float* __restrict__ partials,
    const float* __restrict__ gm, const float* __restrict__ bm,
    const float* __restrict__ gs, const float* __restrict__ bs,
    float* __restrict__ out)
{
    __shared__ __align__(16) float s_part[8 * 128];   // [slice][a*NC+c]
    __shared__ __align__(16) float s_sums[128];
    __shared__ __align__(16) float s_coef[4 * NC];    // A1,B1,A2,B2

    const int tid = threadIdx.x;

    // phase 1: reduce partials [256][128] -> [128]; 8 slices x 32 float4 cells
    {
        const int cell  = tid & 31;        // float4 cell within the 128-float row
        const int slice = tid >> 5;        // 0..7
        const float4* p4 = (const float4*)partials;
        float4 acc = {0.f, 0.f, 0.f, 0.f};
#pragma unroll 8
        for (int i = 0; i < 32; ++i) {
            const float4 v = p4[(slice * 32 + i) * 32 + cell];
            acc.x += v.x; acc.y += v.y; acc.z += v.z; acc.w += v.w;
        }
        *(float4*)&s_part[(slice * 32 + cell) * 4] = acc;
    }
    __syncthreads();
    if (tid < 32) {
        float4 s = {0.f, 0.f, 0.f, 0.f};
#pragma unroll
        for (int sl = 0; sl < 8; ++sl) {
            const float4 v = ((const float4*)s_part)[sl * 32 + tid];
            s.x += v.x; s.y += v.y; s.z += v.z; s.w += v.w;
        }
        ((float4*)s_sums)[tid] = s;
    }
    __syncthreads();
    if (tid < NC) {
        const float invN = 1.0f / (float)(NB * NT);
        const float mu_m  = s_sums[tid] * invN;
        float var_m = s_sums[32 + tid] * invN - mu_m * mu_m;
        var_m = fmaxf(var_m, 0.0f);
        const float A1 = gm[tid] / sqrtf(var_m + 1e-5f);
        const float B1 = bm[tid] - mu_m * A1;
        const float mu_s  = s_sums[64 + tid] * invN;
        float var_s = s_sums[96 + tid] * invN - mu_s * mu_s;
        var_s = fmaxf(var_s, 0.0f);
        const float A2 = gs[tid] / sqrtf(var_s + 1e-5f);
        const float B2 = bs[tid] - mu_s * A2;
        s_coef[tid]          = A1;
        s_coef[NC + tid]     = B1;
        s_coef[2 * NC + tid] = A2;
        s_coef[3 * NC + tid] = B2;
    }
    __syncthreads();

    // phase 2: writeout 32 rows = 768 float4s, 3 coalesced passes
    const float4* x4  = (const float4*)x;
    const float4* fm4 = (const float4*)f_mean;
    const float4* fs4 = (const float4*)f_std;
    const float4* cf4 = (const float4*)s_coef;   // [0..7]=A1 [8..15]=B1 [16..23]=A2 [24..31]=B2
    float4* out4 = (float4*)out;
    const int base = blockIdx.x * 768;           // block owns rows [blk*32, +32)

#pragma unroll
    for (int k = 0; k < 3; ++k) {
        const int j = base + tid + k * 256;
        const int row = j / 24;
        const int q = j - row * 24;
        float4 v;
        if (q < 8) {
            v = x4[row * 8 + q];
        } else if (q < 16) {
            const int m = q - 8;
            const float4 f = fm4[row * 8 + m];
            const float4 A = cf4[m], Bv = cf4[8 + m];
            v.x = fmaf(f.x, A.x, Bv.x); v.y = fmaf(f.y, A.y, Bv.y);
            v.z = fmaf(f.z, A.z, Bv.z); v.w = fmaf(f.w, A.w, Bv.w);
        } else {
            const int m = q - 16;
            const float4 f = fs4[row * 8 + m];
            const float4 A = cf4[16 + m], Bv = cf4[24 + m];
            v.x = fmaf(f.x, A.x, Bv.x); v.y = fmaf(f.y, A.y, Bv.y);
            v.z = fmaf(f.z, A.z, Bv.z); v.w = fmaf(f.w, A.w, Bv.w);
        }
        out4[j] = v;
    }
}

extern "C" void kernel_launch(void* const* d_in, const int* in_sizes, int n_in,
                              void* d_out, int out_size, void* d_ws, size_t ws_size,
                              hipStream_t stream) {
    const float* x      = (const float*)d_in[0];
    const float* series = (const float*)d_in[1];
    const int*   idx    = (const int*)d_in[2];
    const float* rwm    = (const float*)d_in[3];
    const float* rws    = (const float*)d_in[4];
    const float* gm     = (const float*)d_in[5];
    const float* bm     = (const float*)d_in[6];
    const float* gs     = (const float*)d_in[7];
    const float* bs     = (const float*)d_in[8];
    float* out = (float*)d_out;
    float* ws  = (float*)d_ws;

    float* f_mean   = ws + WS_FMEAN;
    float* f_std    = ws + WS_FSTD;
    float* partials = ws + WS_PART;

    feat_main<<<NBLK, 256, 0, stream>>>(series, idx, rwm, rws, f_mean, f_std, partials);
    bn_write<<<NBLK, 256, 0, stream>>>(x, f_mean, f_std, partials, gm, bm, gs, bs, out);
}

// Round 9
// 17.292 us; speedup vs baseline: 1.8898x; 1.0602x over previous
//
#include <hip/hip_runtime.h>
#include <math.h>

#define NB 16          // batch
#define NT 512         // time
#define NC 32          // channels
#define NW 128         // window
#define TILE_T 32
#define NTILES (NT / TILE_T)        // 16
#define NBLK (NB * NTILES)          // 256 blocks -> one per CU
#define NROWS (TILE_T + NW)         // 160 rows staged per block
#define WIN_MIN_F 2.0f
#define WIN_RANGE_F 62.0f
#define EINV_F 0.36787944117f       // e^-1

// ws layout (floats):
#define WS_FMEAN 0
#define WS_FSTD  (NB*NT*NC)
#define WS_PART  (2*NB*NT*NC)       // NBLK * 4 * NC

typedef float v2f __attribute__((ext_vector_type(2)));

__device__ __forceinline__ float fast_sigmoid_neg(float a) {
    return __builtin_amdgcn_rcpf(1.0f + __expf(a));
}
// packed fp32 math via compiler-selected ops (correct op_sel encoding guaranteed)
__device__ __forceinline__ v2f pk_fma(v2f a, v2f b, v2f c) {
    return __builtin_elementwise_fma(a, b, c);
}

__global__ __launch_bounds__(256) void feat_main(
    const float* __restrict__ x,
    const float* __restrict__ series,
    const int*   __restrict__ indices,
    const float* __restrict__ rwm,
    const float* __restrict__ rws,
    float* __restrict__ f_mean,
    float* __restrict__ f_std,
    float* __restrict__ partials,
    float* __restrict__ out)
{
    __shared__ __align__(16) float s_x [NROWS * NC];     // 20 KB row-major [row][c]
    __shared__ __align__(16) float s_w1[NW * NC];        // 16 KB [w][c]
    __shared__ __align__(16) float s_w2[NW * NC];        // 16 KB [w][c]
    __shared__ float s_win[2 * NC];
    __shared__ __align__(16) float s_red[4 * 16 * NC];   // [stat][tg][c], 8 KB

    const int tid = threadIdx.x;
    const int blk = blockIdx.x;
    const int b   = blk >> 4;
    const int tt  = blk & 15;
    const int t0  = tt * TILE_T;
    const int start = indices[2 * b];

    // ---- BN-independent pass-through: out[:, :, 0:32] = x (1 f4 per thread) ----
    {
        const int row = b * NT + t0 + (tid >> 3);
        const int q = tid & 7;
        ((float4*)out)[row * 24 + q] = ((const float4*)x)[row * 8 + q];
    }

    // per-channel soft window sizes
    if (tid < 2 * NC) {
        const float raw = (tid < NC) ? rwm[tid] : rws[tid - NC];
        s_win[tid] = WIN_MIN_F + WIN_RANGE_F * fast_sigmoid_neg(-raw);
    }

    // ---- stage contiguous series slice: rows [start-NW+t0, +NROWS) ----
    const float4* src4 = (const float4*)(series + (size_t)(start - NW + t0) * NC);
    float4* dst4 = (float4*)s_x;
#pragma unroll
    for (int k = 0; k < 5; ++k) {
        const int j = tid + k * 256;       // exactly 1280 float4s
        dst4[j] = src4[j];
    }
    __syncthreads();   // S1

    // ---- weight tables via exp-recurrence: thread owns (c, 16-w chunk) ----
    {
        const int c  = tid & 31;
        const int wc = tid >> 5;           // 0..7
        const int w0 = wc * 16;
        const float age0 = (float)(NW - 1 - w0);
        float E1 = __expf(age0 - s_win[c]);
        float E2 = __expf(age0 - s_win[NC + c]);
#pragma unroll
        for (int j = 0; j < 16; ++j) {
            const int idx = (w0 + j) * NC + c;
            s_w1[idx] = __builtin_amdgcn_rcpf(1.0f + E1);
            s_w2[idx] = __builtin_amdgcn_rcpf(1.0f + E2);
            E1 *= EINV_F;
            E2 *= EINV_F;
        }
    }
    __syncthreads();   // S2

    // ---- main loop: thread owns (channel-pair cp, 2 rows); float2 math ----
    const int cp = tid & 15;           // channel pair: channels 2cp, 2cp+1
    const int tg = tid >> 4;           // 0..15, rows r0, r0+1
    const int r0 = tg * 2;

    const v2f* xv  = (const v2f*)s_x;    // elem idx = row*16 + cp
    const v2f* w1v = (const v2f*)s_w1;   // elem idx = w*16 + cp
    const v2f* w2v = (const v2f*)s_w2;

    v2f a1_0 = {0.f,0.f}, a2_0 = {0.f,0.f}, a3_0 = {0.f,0.f};
    v2f a1_1 = {0.f,0.f}, a2_1 = {0.f,0.f}, a3_1 = {0.f,0.f};
    v2f sw1 = {0.f,0.f}, sw2 = {0.f,0.f};

    v2f x0 = xv[(r0 + 0) * 16 + cp];
    v2f x1 = xv[(r0 + 1) * 16 + cp];
    v2f q0 = x0 * x0;
    v2f q1 = x1 * x1;

#pragma unroll 4
    for (int w = 0; w < NW; ++w) {
        const v2f wv1 = w1v[w * 16 + cp];
        const v2f wv2 = w2v[w * 16 + cp];
        sw1 = sw1 + wv1;
        sw2 = sw2 + wv2;
        a1_0 = pk_fma(x0, wv1, a1_0);
        a2_0 = pk_fma(x0, wv2, a2_0);
        a3_0 = pk_fma(q0, wv2, a3_0);
        a1_1 = pk_fma(x1, wv1, a1_1);
        a2_1 = pk_fma(x1, wv2, a2_1);
        a3_1 = pk_fma(q1, wv2, a3_1);
        const v2f xn = xv[(r0 + 2 + w) * 16 + cp];   // max row 159: in bounds
        x0 = x1; q0 = q1;
        x1 = xn; q1 = xn * xn;
    }

    v2f inv1, inv2;
    inv1.x = __builtin_amdgcn_rcpf(sw1.x); inv1.y = __builtin_amdgcn_rcpf(sw1.y);
    inv2.x = __builtin_amdgcn_rcpf(sw2.x); inv2.y = __builtin_amdgcn_rcpf(sw2.y);

    v2f p0 = {0.f,0.f}, p1 = {0.f,0.f}, p2 = {0.f,0.f}, p3 = {0.f,0.f};
#pragma unroll
    for (int k = 0; k < 2; ++k) {
        const v2f A1 = k ? a1_1 : a1_0;
        const v2f A2 = k ? a2_1 : a2_0;
        const v2f A3 = k ? a3_1 : a3_0;
        const v2f fm = A1 * inv1;
        const v2f m2 = A2 * inv2;
        const v2f e2 = A3 * inv2;
        v2f fs;
        fs.x = sqrtf(fmaxf(e2.x - m2.x * m2.x, 0.f) + 1e-8f);
        fs.y = sqrtf(fmaxf(e2.y - m2.y * m2.y, 0.f) + 1e-8f);
        const int row = t0 + r0 + k;
        const size_t o2 = ((size_t)b * NT + row) * 16 + cp;
        ((v2f*)f_mean)[o2] = fm;
        ((v2f*)f_std)[o2]  = fs;
        p0 = p0 + fm;
        p1 = pk_fma(fm, fm, p1);
        p2 = p2 + fs;
        p3 = pk_fma(fs, fs, p3);
    }

    v2f* redv = (v2f*)s_red;   // [stat][tg][cp]
    redv[(0 * 16 + tg) * 16 + cp] = p0;
    redv[(1 * 16 + tg) * 16 + cp] = p1;
    redv[(2 * 16 + tg) * 16 + cp] = p2;
    redv[(3 * 16 + tg) * 16 + cp] = p3;
    __syncthreads();   // S3

    if (tid < 64) {
        const int stat = tid >> 4, cc = tid & 15;
        v2f s = {0.f, 0.f};
#pragma unroll
        for (int g = 0; g < 16; ++g)
            s = s + redv[(stat * 16 + g) * 16 + cc];
        ((v2f*)partials)[blk * 64 + stat * 16 + cc] = s;
    }
}

// BN-reduce (redundant per block) + float4 writeout of BN cols. 256 blocks x 256 thr.
__global__ __launch_bounds__(256) void bn_write(
    const float* __restrict__ f_mean,
    const float* __restrict__ f_std,
    const float* __restrict__ partials,
    const float* __restrict__ gm, const float* __restrict__ bm,
    const float* __restrict__ gs, const float* __restrict__ bs,
    float* __restrict__ out)
{
    __shared__ __align__(16) float s_part[8 * 128];
    __shared__ __align__(16) float s_sums[128];
    __shared__ __align__(16) float s_coef[4 * NC];    // A1,B1,A2,B2

    const int tid = threadIdx.x;

    // phase 1: reduce partials [256][128] -> [128]; 8 slices x 32 float4 cells
    {
        const int cell  = tid & 31;
        const int slice = tid >> 5;
        const float4* p4 = (const float4*)partials;
        float4 acc = {0.f, 0.f, 0.f, 0.f};
#pragma unroll 8
        for (int i = 0; i < 32; ++i) {
            const float4 v = p4[(slice * 32 + i) * 32 + cell];
            acc.x += v.x; acc.y += v.y; acc.z += v.z; acc.w += v.w;
        }
        *(float4*)&s_part[(slice * 32 + cell) * 4] = acc;
    }
    __syncthreads();
    if (tid < 32) {
        float4 s = {0.f, 0.f, 0.f, 0.f};
#pragma unroll
        for (int sl = 0; sl < 8; ++sl) {
            const float4 v = ((const float4*)s_part)[sl * 32 + tid];
            s.x += v.x; s.y += v.y; s.z += v.z; s.w += v.w;
        }
        ((float4*)s_sums)[tid] = s;
    }
    __syncthreads();
    if (tid < NC) {
        const float invN = 1.0f / (float)(NB * NT);
        const float mu_m  = s_sums[tid] * invN;
        float var_m = s_sums[32 + tid] * invN - mu_m * mu_m;
        var_m = fmaxf(var_m, 0.0f);
        const float A1 = gm[tid] / sqrtf(var_m + 1e-5f);
        const float B1 = bm[tid] - mu_m * A1;
        const float mu_s  = s_sums[64 + tid] * invN;
        float var_s = s_sums[96 + tid] * invN - mu_s * mu_s;
        var_s = fmaxf(var_s, 0.0f);
        const float A2 = gs[tid] / sqrtf(var_s + 1e-5f);
        const float B2 = bs[tid] - mu_s * A2;
        s_coef[tid]          = A1;
        s_coef[NC + tid]     = B1;
        s_coef[2 * NC + tid] = A2;
        s_coef[3 * NC + tid] = B2;
    }
    __syncthreads();

    // phase 2: writeout BN cols: 32 rows x 16 float4 = 512, two coalesced passes
    const float4* fm4 = (const float4*)f_mean;
    const float4* fs4 = (const float4*)f_std;
    const float4* cf4 = (const float4*)s_coef;   // [0..7]=A1 [8..15]=B1 [16..23]=A2 [24..31]=B2
    float4* out4 = (float4*)out;
    const int row0 = blockIdx.x * 32;

#pragma unroll
    for (int k = 0; k < 2; ++k) {
        const int j = tid + k * 256;
        const int r = j >> 4;
        const int q = j & 15;
        const int row = row0 + r;
        float4 v;
        int oq;
        if (q < 8) {
            const float4 f = fm4[row * 8 + q];
            const float4 A = cf4[q], Bv = cf4[8 + q];
            v.x = fmaf(f.x, A.x, Bv.x); v.y = fmaf(f.y, A.y, Bv.y);
            v.z = fmaf(f.z, A.z, Bv.z); v.w = fmaf(f.w, A.w, Bv.w);
            oq = 8 + q;
        } else {
            const int m = q - 8;
            const float4 f = fs4[row * 8 + m];
            const float4 A = cf4[16 + m], Bv = cf4[24 + m];
            v.x = fmaf(f.x, A.x, Bv.x); v.y = fmaf(f.y, A.y, Bv.y);
            v.z = fmaf(f.z, A.z, Bv.z); v.w = fmaf(f.w, A.w, Bv.w);
            oq = 16 + m;
        }
        out4[row * 24 + oq] = v;
    }
}

extern "C" void kernel_launch(void* const* d_in, const int* in_sizes, int n_in,
                              void* d_out, int out_size, void* d_ws, size_t ws_size,
                              hipStream_t stream) {
    const float* x      = (const float*)d_in[0];
    const float* series = (const float*)d_in[1];
    const int*   idx    = (const int*)d_in[2];
    const float* rwm    = (const float*)d_in[3];
    const float* rws    = (const float*)d_in[4];
    const float* gm     = (const float*)d_in[5];
    const float* bm     = (const float*)d_in[6];
    const float* gs     = (const float*)d_in[7];
    const float* bs     = (const float*)d_in[8];
    float* out = (float*)d_out;
    float* ws  = (float*)d_ws;

    float* f_mean   = ws + WS_FMEAN;
    float* f_std    = ws + WS_FSTD;
    float* partials = ws + WS_PART;

    feat_main<<<NBLK, 256, 0, stream>>>(x, series, idx, rwm, rws, f_mean, f_std, partials, out);
    bn_write<<<NBLK, 256, 0, stream>>>(f_mean, f_std, partials, gm, bm, gs, bs, out);
}

// Round 10
// 15.699 us; speedup vs baseline: 2.0814x; 1.1014x over previous
//
#include <hip/hip_runtime.h>
#include <math.h>

#define NB 16          // batch
#define NT 512         // time
#define NC 32          // channels
#define NW 128         // window
#define TILE_T 32
#define NTILES (NT / TILE_T)        // 16
#define NBLK (NB * NTILES)          // 256 blocks -> one per CU
#define NROWS (TILE_T + NW)         // 160 rows staged per block
#define XS 36                       // x row stride in floats (144B: 16B-aligned, rg-groups 2-way banks)
#define WIN_MIN_F 2.0f
#define WIN_RANGE_F 62.0f
#define EINV_F 0.36787944117f       // e^-1

// ws layout (floats):
#define WS_FMEAN 0
#define WS_FSTD  (NB*NT*NC)
#define WS_PART  (2*NB*NT*NC)       // NBLK * 4 * NC

typedef float v2f __attribute__((ext_vector_type(2)));

__device__ __forceinline__ float fast_sigmoid_neg(float a) {
    return __builtin_amdgcn_rcpf(1.0f + __expf(a));
}
__device__ __forceinline__ v2f pk_fma(v2f a, v2f b, v2f c) {
    return __builtin_elementwise_fma(a, b, c);
}

// s_u overlay offsets (floats): weight table [0,8192) while looping;
// after S3a it is reused: s_m at 0 (3072 floats), s_swh at 3072 (64), s_red at 3200 (1024)
#define U_M    0
#define U_SWH  3072
#define U_RED  3200

__global__ __launch_bounds__(256) void feat_main(
    const float* __restrict__ x,
    const float* __restrict__ series,
    const int*   __restrict__ indices,
    const float* __restrict__ rwm,
    const float* __restrict__ rws,
    float* __restrict__ f_mean,
    float* __restrict__ f_std,
    float* __restrict__ partials,
    float* __restrict__ out)
{
    __shared__ __align__(16) float s_x[NROWS * XS];   // 23 KB, [row][c] stride 36
    __shared__ __align__(16) float s_u[NW * 64];      // 32 KB: w12 table / merge arena
    __shared__ float s_win[2 * NC];

    const int tid = threadIdx.x;
    const int blk = blockIdx.x;
    const int b   = blk >> 4;
    const int tt  = blk & 15;
    const int t0  = tt * TILE_T;
    const int start = indices[2 * b];

    // ---- BN-independent pass-through: out[:, :, 0:32] = x (1 f4 per thread) ----
    {
        const int row = b * NT + t0 + (tid >> 3);
        const int q = tid & 7;
        ((float4*)out)[row * 24 + q] = ((const float4*)x)[row * 8 + q];
    }

    // per-channel soft window sizes
    if (tid < 2 * NC) {
        const float raw = (tid < NC) ? rwm[tid] : rws[tid - NC];
        s_win[tid] = WIN_MIN_F + WIN_RANGE_F * fast_sigmoid_neg(-raw);
    }

    // ---- stage series slice rows [start-NW+t0, +NROWS), stride XS ----
    const float4* src4 = (const float4*)(series + (size_t)(start - NW + t0) * NC);
#pragma unroll
    for (int k = 0; k < 5; ++k) {
        const int j = tid + k * 256;          // exactly 1280 float4s
        const int row = j >> 3, c4 = (j & 7) << 2;
        *(float4*)&s_x[row * XS + c4] = src4[j];
    }
    __syncthreads();   // S1: s_win + tile visible

    // ---- fused weight table s_u[w][cp]: f4 = (w1[2cp],w1[2cp+1],w2[2cp],w2[2cp+1]) ----
    {
        const int c  = tid & 31;
        const int wc = tid >> 5;              // 0..7, w-chunk of 16
        const int w0t = wc * 16;
        const float age0 = (float)(NW - 1 - w0t);
        float E1 = __expf(age0 - s_win[c]);
        float E2 = __expf(age0 - s_win[NC + c]);
#pragma unroll
        for (int j = 0; j < 16; ++j) {
            const int base = (w0t + j) * 64 + (c >> 1) * 4 + (c & 1);
            s_u[base]     = __builtin_amdgcn_rcpf(1.0f + E1);   // w1
            s_u[base + 2] = __builtin_amdgcn_rcpf(1.0f + E2);   // w2
            E1 *= EINV_F;
            E2 *= EINV_F;
        }
    }
    __syncthreads();   // S2: table visible

    // ---- main loop: thread = (cp, 4 rows rg, w-half); 2 LDS ops/iter ----
    const int cp   = tid & 15;            // channel pair
    const int tg   = tid >> 4;            // 0..15
    const int half = tg >> 3;             // 0/1 -> w in [64*half, 64*half+64)
    const int rg   = tg & 7;              // row group: rows rg*4..rg*4+3
    const int r0   = rg * 4;
    const int base = r0 + half * 64;      // first s_x row this thread touches

    const v2f*    xv2 = (const v2f*)s_x;      // idx = row*18 + cp
    const float4* wv4 = (const float4*)s_u;   // idx = w*16 + cp

    v2f a1[4], a2[4], a3[4];
#pragma unroll
    for (int k = 0; k < 4; ++k) { a1[k] = (v2f){0.f,0.f}; a2[k] = (v2f){0.f,0.f}; a3[k] = (v2f){0.f,0.f}; }
    v2f sw1 = {0.f,0.f}, sw2 = {0.f,0.f};

    v2f xs[4], qs[4];
#pragma unroll
    for (int k = 0; k < 4; ++k) {
        xs[k] = xv2[(base + k) * 18 + cp];
        qs[k] = xs[k] * xs[k];
    }

    const int w0 = half * 64;
#pragma unroll 4
    for (int i = 0; i < 64; ++i) {
        const float4 wv = wv4[(w0 + i) * 16 + cp];
        const v2f wlo = {wv.x, wv.y};         // w1 pair
        const v2f whi = {wv.z, wv.w};         // w2 pair
        sw1 = sw1 + wlo;
        sw2 = sw2 + whi;
#pragma unroll
        for (int k = 0; k < 4; ++k) {
            a1[k] = pk_fma(xs[k], wlo, a1[k]);
            a2[k] = pk_fma(xs[k], whi, a2[k]);
            a3[k] = pk_fma(qs[k], whi, a3[k]);
        }
        const v2f xn = xv2[(base + i + 4) * 18 + cp];   // max row 159: in bounds
        xs[0] = xs[1]; qs[0] = qs[1];
        xs[1] = xs[2]; qs[1] = qs[2];
        xs[2] = xs[3]; qs[2] = qs[3];
        xs[3] = xn;    qs[3] = xn * xn;
    }

    __syncthreads();   // S3a: all done with the weight table -> s_u reusable

    v2f* s_m   = (v2f*)&s_u[U_M];     // [rg*16+cp][12]
    v2f* s_swh = (v2f*)&s_u[U_SWH];   // [cp][2]
    v2f* s_red = (v2f*)&s_u[U_RED];   // [stat][rg][cp]

    if (half) {
        v2f* m = &s_m[(rg * 16 + cp) * 12];
#pragma unroll
        for (int k = 0; k < 4; ++k) {
            m[k]     = a1[k];
            m[4 + k] = a2[k];
            m[8 + k] = a3[k];
        }
        if (rg == 0) {
            s_swh[cp * 2]     = sw1;
            s_swh[cp * 2 + 1] = sw2;
        }
    }
    __syncthreads();   // S3b: half-1 contributions visible

    if (!half) {
        const v2f* m = &s_m[(rg * 16 + cp) * 12];
#pragma unroll
        for (int k = 0; k < 4; ++k) {
            a1[k] = a1[k] + m[k];
            a2[k] = a2[k] + m[4 + k];
            a3[k] = a3[k] + m[8 + k];
        }
        sw1 = sw1 + s_swh[cp * 2];
        sw2 = sw2 + s_swh[cp * 2 + 1];

        v2f inv1, inv2;
        inv1.x = __builtin_amdgcn_rcpf(sw1.x); inv1.y = __builtin_amdgcn_rcpf(sw1.y);
        inv2.x = __builtin_amdgcn_rcpf(sw2.x); inv2.y = __builtin_amdgcn_rcpf(sw2.y);

        v2f p0 = {0.f,0.f}, p1 = {0.f,0.f}, p2 = {0.f,0.f}, p3 = {0.f,0.f};
#pragma unroll
        for (int k = 0; k < 4; ++k) {
            const v2f fm = a1[k] * inv1;
            const v2f m2 = a2[k] * inv2;
            const v2f e2 = a3[k] * inv2;
            v2f fs;
            fs.x = sqrtf(fmaxf(e2.x - m2.x * m2.x, 0.f) + 1e-8f);
            fs.y = sqrtf(fmaxf(e2.y - m2.y * m2.y, 0.f) + 1e-8f);
            const size_t o2 = ((size_t)(b * NT + t0 + r0 + k)) * 16 + cp;
            ((v2f*)f_mean)[o2] = fm;
            ((v2f*)f_std)[o2]  = fs;
            p0 = p0 + fm;
            p1 = pk_fma(fm, fm, p1);
            p2 = p2 + fs;
            p3 = pk_fma(fs, fs, p3);
        }
        s_red[(0 * 8 + rg) * 16 + cp] = p0;
        s_red[(1 * 8 + rg) * 16 + cp] = p1;
        s_red[(2 * 8 + rg) * 16 + cp] = p2;
        s_red[(3 * 8 + rg) * 16 + cp] = p3;
    }
    __syncthreads();   // S4

    if (tid < 64) {
        const int stat = tid >> 4, cc = tid & 15;
        v2f s = {0.f, 0.f};
#pragma unroll
        for (int g = 0; g < 8; ++g)
            s = s + s_red[(stat * 8 + g) * 16 + cc];
        ((v2f*)partials)[blk * 64 + stat * 16 + cc] = s;
    }
}

// BN-reduce (redundant per block) + float4 writeout of BN cols. 256 blocks x 256 thr.
__global__ __launch_bounds__(256) void bn_write(
    const float* __restrict__ f_mean,
    const float* __restrict__ f_std,
    const float* __restrict__ partials,
    const float* __restrict__ gm, const float* __restrict__ bm,
    const float* __restrict__ gs, const float* __restrict__ bs,
    float* __restrict__ out)
{
    __shared__ __align__(16) float s_part[8 * 128];
    __shared__ __align__(16) float s_sums[128];
    __shared__ __align__(16) float s_coef[4 * NC];    // A1,B1,A2,B2

    const int tid = threadIdx.x;

    // phase 1: reduce partials [256][128] -> [128]; 8 slices x 32 float4 cells
    {
        const int cell  = tid & 31;
        const int slice = tid >> 5;
        const float4* p4 = (const float4*)partials;
        float4 acc = {0.f, 0.f, 0.f, 0.f};
#pragma unroll 8
        for (int i = 0; i < 32; ++i) {
            const float4 v = p4[(slice * 32 + i) * 32 + cell];
            acc.x += v.x; acc.y += v.y; acc.z += v.z; acc.w += v.w;
        }
        *(float4*)&s_part[(slice * 32 + cell) * 4] = acc;
    }
    __syncthreads();
    if (tid < 32) {
        float4 s = {0.f, 0.f, 0.f, 0.f};
#pragma unroll
        for (int sl = 0; sl < 8; ++sl) {
            const float4 v = ((const float4*)s_part)[sl * 32 + tid];
            s.x += v.x; s.y += v.y; s.z += v.z; s.w += v.w;
        }
        ((float4*)s_sums)[tid] = s;
    }
    __syncthreads();
    if (tid < NC) {
        const float invN = 1.0f / (float)(NB * NT);
        const float mu_m  = s_sums[tid] * invN;
        float var_m = s_sums[32 + tid] * invN - mu_m * mu_m;
        var_m = fmaxf(var_m, 0.0f);
        const float A1 = gm[tid] / sqrtf(var_m + 1e-5f);
        const float B1 = bm[tid] - mu_m * A1;
        const float mu_s  = s_sums[64 + tid] * invN;
        float var_s = s_sums[96 + tid] * invN - mu_s * mu_s;
        var_s = fmaxf(var_s, 0.0f);
        const float A2 = gs[tid] / sqrtf(var_s + 1e-5f);
        const float B2 = bs[tid] - mu_s * A2;
        s_coef[tid]          = A1;
        s_coef[NC + tid]     = B1;
        s_coef[2 * NC + tid] = A2;
        s_coef[3 * NC + tid] = B2;
    }
    __syncthreads();

    // phase 2: writeout BN cols: 32 rows x 16 float4 = 512, two coalesced passes
    const float4* fm4 = (const float4*)f_mean;
    const float4* fs4 = (const float4*)f_std;
    const float4* cf4 = (const float4*)s_coef;   // [0..7]=A1 [8..15]=B1 [16..23]=A2 [24..31]=B2
    float4* out4 = (float4*)out;
    const int row0 = blockIdx.x * 32;

#pragma unroll
    for (int k = 0; k < 2; ++k) {
        const int j = tid + k * 256;
        const int r = j >> 4;
        const int q = j & 15;
        const int row = row0 + r;
        float4 v;
        int oq;
        if (q < 8) {
            const float4 f = fm4[row * 8 + q];
            const float4 A = cf4[q], Bv = cf4[8 + q];
            v.x = fmaf(f.x, A.x, Bv.x); v.y = fmaf(f.y, A.y, Bv.y);
            v.z = fmaf(f.z, A.z, Bv.z); v.w = fmaf(f.w, A.w, Bv.w);
            oq = 8 + q;
        } else {
            const int m = q - 8;
            const float4 f = fs4[row * 8 + m];
            const float4 A = cf4[16 + m], Bv = cf4[24 + m];
            v.x = fmaf(f.x, A.x, Bv.x); v.y = fmaf(f.y, A.y, Bv.y);
            v.z = fmaf(f.z, A.z, Bv.z); v.w = fmaf(f.w, A.w, Bv.w);
            oq = 16 + m;
        }
        out4[row * 24 + oq] = v;
    }
}

extern "C" void kernel_launch(void* const* d_in, const int* in_sizes, int n_in,
                              void* d_out, int out_size, void* d_ws, size_t ws_size,
                              hipStream_t stream) {
    const float* x      = (const float*)d_in[0];
    const float* series = (const float*)d_in[1];
    const int*   idx    = (const int*)d_in[2];
    const float* rwm    = (const float*)d_in[3];
    const float* rws    = (const float*)d_in[4];
    const float* gm     = (const float*)d_in[5];
    const float* bm     = (const float*)d_in[6];
    const float* gs     = (const float*)d_in[7];
    const float* bs     = (const float*)d_in[8];
    float* out = (float*)d_out;
    float* ws  = (float*)d_ws;

    float* f_mean   = ws + WS_FMEAN;
    float* f_std    = ws + WS_FSTD;
    float* partials = ws + WS_PART;

    feat_main<<<NBLK, 256, 0, stream>>>(x, series, idx, rwm, rws, f_mean, f_std, partials, out);
    bn_write<<<NBLK, 256, 0, stream>>>(f_mean, f_std, partials, gm, bm, gs, bs, out);
}